// Round 1
// baseline (1100.768 us; speedup 1.0000x reference)
//
#include <hip/hip_runtime.h>
#include <math.h>

#define T_CONST 2048
#define D_CONST 1024
#define I_CONST 512
#define SI_CONST 1024
#define E_CONST 32
#define G_CONST 8
#define LG_CONST 4
#define KSEL 6

// ---------------- Router ----------------
// One block per token. Compute 32 logits, softmax, group-limited top-k,
// scatter (slot, gate) into per-expert lists.
__global__ __launch_bounds__(256) void router_kernel(
    const float* __restrict__ x, const float* __restrict__ rw,
    const float* __restrict__ rb, int* __restrict__ counts,
    int* __restrict__ slots, float* __restrict__ gatel) {
  int t = blockIdx.x;
  __shared__ float sx[D_CONST];
  __shared__ float slog[E_CONST];
  int tid = threadIdx.x;
  for (int i = tid; i < D_CONST; i += 256) sx[i] = x[(size_t)t * D_CONST + i];
  __syncthreads();
  int e = tid >> 3, l8 = tid & 7;
  float s = 0.f;
  const float* rwp = rw + (size_t)e * D_CONST;
  for (int d = l8; d < D_CONST; d += 8) s += sx[d] * rwp[d];
  s += __shfl_xor(s, 4, 8);
  s += __shfl_xor(s, 2, 8);
  s += __shfl_xor(s, 1, 8);
  if (l8 == 0) slog[e] = s + rb[e];
  __syncthreads();
  if (tid == 0) {
    float sc[E_CONST];
    float mx = -1e30f;
    for (int i = 0; i < E_CONST; ++i) mx = fmaxf(mx, slog[i]);
    float sum = 0.f;
    for (int i = 0; i < E_CONST; ++i) { sc[i] = expf(slog[i] - mx); sum += sc[i]; }
    float inv = 1.f / sum;
    for (int i = 0; i < E_CONST; ++i) sc[i] *= inv;
    // group scores = sum of top-2 within each group of 4
    float gs[G_CONST];
    for (int g = 0; g < G_CONST; ++g) {
      float m1 = -1e30f, m2 = -1e30f;
      for (int j = 0; j < 4; ++j) {
        float v = sc[g * 4 + j];
        if (v > m1) { m2 = m1; m1 = v; }
        else if (v > m2) { m2 = v; }
      }
      gs[g] = m1 + m2;
    }
    bool keep[G_CONST];
    for (int g = 0; g < G_CONST; ++g) keep[g] = false;
    float tmp[G_CONST];
    for (int g = 0; g < G_CONST; ++g) tmp[g] = gs[g];
    for (int r = 0; r < LG_CONST; ++r) {
      int bi = -1; float bv = -1e30f;
      for (int g = 0; g < G_CONST; ++g)
        if (tmp[g] > bv) { bv = tmp[g]; bi = g; }
      keep[bi] = true; tmp[bi] = -1e30f;
    }
    bool taken[E_CONST];
    for (int i = 0; i < E_CONST; ++i) taken[i] = false;
    for (int r = 0; r < KSEL; ++r) {
      int bi = -1; float bv = -1e30f;
      for (int i = 0; i < E_CONST; ++i)
        if (keep[i >> 2] && !taken[i] && sc[i] > bv) { bv = sc[i]; bi = i; }
      taken[bi] = true;
      int pos = atomicAdd(&counts[bi], 1);
      slots[bi * T_CONST + pos] = t * KSEL + r;
      gatel[bi * T_CONST + pos] = sc[bi];
    }
  }
}

// ---------------- Fused up-projection (W1 & W2, silu(h1*h2)) ----------------
// C[m][n] -> Hout[dst[m]][n] = silu((A@B1+bias1)*(A@B2+bias2))
// GATHER: A rows gathered by expert token list; B offset by expert.
template <bool GATHER>
__global__ __launch_bounds__(256) void up_proj(
    const float* __restrict__ X, const float* __restrict__ B1w,
    const float* __restrict__ B2w, const float* __restrict__ bias1,
    const float* __restrict__ bias2, const int* __restrict__ counts,
    const int* __restrict__ slots, float* __restrict__ Hout, int N) {
  const int e = GATHER ? blockIdx.z : 0;
  const int cnt = GATHER ? counts[e] : T_CONST;
  const int m0 = blockIdx.y * 64;
  if (m0 >= cnt) return;
  const int n0 = blockIdx.x * 64;

  __shared__ float As[16][64];
  __shared__ float Bs1[16][64];
  __shared__ float Bs2[16][64];
  __shared__ int srow[64];
  __shared__ int sdst[64];

  const int tid = threadIdx.x;
  if (tid < 64) {
    int r = m0 + tid;
    bool valid = r < cnt;
    int tok = 0, dst = -1;
    if (GATHER) {
      int sl = valid ? slots[e * T_CONST + r] : 0;
      tok = sl / KSEL;
      dst = valid ? sl : -1;
    } else {
      tok = valid ? r : 0;
      dst = valid ? r : -1;
    }
    srow[tid] = tok;
    sdst[tid] = dst;
  }
  __syncthreads();

  const float* W1p = B1w + (size_t)e * D_CONST * N;
  const float* W2p = B2w + (size_t)e * D_CONST * N;

  float acc1[4][4] = {{0.f}}, acc2[4][4] = {{0.f}};
  const int tx = tid & 15, ty = tid >> 4;
  const int lm = tid >> 2, lk4 = (tid & 3) * 4;
  const int lk = tid >> 4, ln4 = (tid & 15) * 4;
  const int tokA = srow[lm];

  for (int kk = 0; kk < D_CONST; kk += 16) {
    float4 av = *(const float4*)&X[(size_t)tokA * D_CONST + kk + lk4];
    As[lk4 + 0][lm] = av.x;
    As[lk4 + 1][lm] = av.y;
    As[lk4 + 2][lm] = av.z;
    As[lk4 + 3][lm] = av.w;
    *(float4*)&Bs1[lk][ln4] = *(const float4*)&W1p[(size_t)(kk + lk) * N + n0 + ln4];
    *(float4*)&Bs2[lk][ln4] = *(const float4*)&W2p[(size_t)(kk + lk) * N + n0 + ln4];
    __syncthreads();
#pragma unroll
    for (int k = 0; k < 16; ++k) {
      float4 a = *(const float4*)&As[k][ty * 4];
      float4 b1 = *(const float4*)&Bs1[k][tx * 4];
      float4 b2 = *(const float4*)&Bs2[k][tx * 4];
      float av_[4] = {a.x, a.y, a.z, a.w};
      float b1_[4] = {b1.x, b1.y, b1.z, b1.w};
      float b2_[4] = {b2.x, b2.y, b2.z, b2.w};
#pragma unroll
      for (int i = 0; i < 4; ++i)
#pragma unroll
        for (int j = 0; j < 4; ++j) {
          acc1[i][j] += av_[i] * b1_[j];
          acc2[i][j] += av_[i] * b2_[j];
        }
    }
    __syncthreads();
  }

  const float* bb1 = bias1 + (size_t)e * N + n0;
  const float* bb2 = bias2 + (size_t)e * N + n0;
#pragma unroll
  for (int i = 0; i < 4; ++i) {
    int lr = ty * 4 + i;
    int dst = sdst[lr];
    if (dst < 0) continue;
#pragma unroll
    for (int j = 0; j < 4; ++j) {
      int n = tx * 4 + j;
      float p = (acc1[i][j] + bb1[n]) * (acc2[i][j] + bb2[n]);
      float h = p / (1.f + expf(-p));
      Hout[(size_t)dst * N + n0 + n] = h;
    }
  }
}

// ---------------- Down projection ----------------
// ROUTED: Out[tok][n] += gate * (H@W3[e] + b3[e])   (atomic)
// else:   Out[tok][n]  = Hs@sw3 + sb3               (plain store, runs first)
template <bool ROUTED>
__global__ __launch_bounds__(256) void down_proj(
    const float* __restrict__ Hin, const float* __restrict__ Wd,
    const float* __restrict__ bd, const int* __restrict__ counts,
    const int* __restrict__ slots, const float* __restrict__ gatel,
    float* __restrict__ Out, int Kdim) {
  const int e = ROUTED ? blockIdx.z : 0;
  const int cnt = ROUTED ? counts[e] : T_CONST;
  const int m0 = blockIdx.y * 64;
  if (m0 >= cnt) return;
  const int n0 = blockIdx.x * 64;

  __shared__ float As[16][64];
  __shared__ float Bs[16][64];
  __shared__ int ssrc[64];
  __shared__ int stok[64];
  __shared__ float sg[64];

  const int tid = threadIdx.x;
  if (tid < 64) {
    int r = m0 + tid;
    bool valid = r < cnt;
    if (ROUTED) {
      int sl = valid ? slots[e * T_CONST + r] : 0;
      ssrc[tid] = sl;
      stok[tid] = valid ? (sl / KSEL) : -1;
      sg[tid] = valid ? gatel[e * T_CONST + r] : 0.f;
    } else {
      ssrc[tid] = valid ? r : 0;
      stok[tid] = valid ? r : -1;
      sg[tid] = 1.f;
    }
  }
  __syncthreads();

  const float* Wp = Wd + (size_t)e * Kdim * D_CONST;

  float acc[4][4] = {{0.f}};
  const int tx = tid & 15, ty = tid >> 4;
  const int lm = tid >> 2, lk4 = (tid & 3) * 4;
  const int lk = tid >> 4, ln4 = (tid & 15) * 4;
  const int srcA = ssrc[lm];

  for (int kk = 0; kk < Kdim; kk += 16) {
    float4 av = *(const float4*)&Hin[(size_t)srcA * Kdim + kk + lk4];
    As[lk4 + 0][lm] = av.x;
    As[lk4 + 1][lm] = av.y;
    As[lk4 + 2][lm] = av.z;
    As[lk4 + 3][lm] = av.w;
    *(float4*)&Bs[lk][ln4] = *(const float4*)&Wp[(size_t)(kk + lk) * D_CONST + n0 + ln4];
    __syncthreads();
#pragma unroll
    for (int k = 0; k < 16; ++k) {
      float4 a = *(const float4*)&As[k][ty * 4];
      float4 b = *(const float4*)&Bs[k][tx * 4];
      float av_[4] = {a.x, a.y, a.z, a.w};
      float b_[4] = {b.x, b.y, b.z, b.w};
#pragma unroll
      for (int i = 0; i < 4; ++i)
#pragma unroll
        for (int j = 0; j < 4; ++j) acc[i][j] += av_[i] * b_[j];
    }
    __syncthreads();
  }

#pragma unroll
  for (int i = 0; i < 4; ++i) {
    int lr = ty * 4 + i;
    int tok = stok[lr];
    if (tok < 0) continue;
#pragma unroll
    for (int j = 0; j < 4; ++j) {
      int n = n0 + tx * 4 + j;
      if (ROUTED) {
        float v = sg[lr] * (acc[i][j] + bd[(size_t)e * D_CONST + n]);
        atomicAdd(&Out[(size_t)tok * D_CONST + n], v);
      } else {
        Out[(size_t)tok * D_CONST + n] = acc[i][j] + bd[n];
      }
    }
  }
}

extern "C" void kernel_launch(void* const* d_in, const int* in_sizes, int n_in,
                              void* d_out, int out_size, void* d_ws, size_t ws_size,
                              hipStream_t stream) {
  const float* x   = (const float*)d_in[0];
  const float* rw  = (const float*)d_in[1];
  const float* rb  = (const float*)d_in[2];
  const float* W1  = (const float*)d_in[3];
  const float* b1  = (const float*)d_in[4];
  const float* W2  = (const float*)d_in[5];
  const float* b2  = (const float*)d_in[6];
  const float* W3  = (const float*)d_in[7];
  const float* b3  = (const float*)d_in[8];
  const float* sw1 = (const float*)d_in[9];
  const float* sb1 = (const float*)d_in[10];
  const float* sw2 = (const float*)d_in[11];
  const float* sb2 = (const float*)d_in[12];
  const float* sw3 = (const float*)d_in[13];
  const float* sb3 = (const float*)d_in[14];
  float* out = (float*)d_out;

  char* w = (char*)d_ws;
  int* counts = (int*)w;                                   // 256 B
  int* slots = (int*)(w + 256);                            // E*T*4
  float* gatel = (float*)(w + 256 + E_CONST * T_CONST * 4);
  float* Hbuf = (float*)(w + 256 + 2 * E_CONST * T_CONST * 4);       // T*K*I*4
  float* Hs = (float*)(w + 256 + 2 * E_CONST * T_CONST * 4 +
                       (size_t)T_CONST * KSEL * I_CONST * 4);        // T*SI*4

  hipMemsetAsync(counts, 0, E_CONST * sizeof(int), stream);
  router_kernel<<<T_CONST, 256, 0, stream>>>(x, rw, rb, counts, slots, gatel);
  // routed up-proj: H = silu((Xg@W1+b1)*(Xg@W2+b2))
  up_proj<true><<<dim3(I_CONST / 64, T_CONST / 64, E_CONST), 256, 0, stream>>>(
      x, W1, W2, b1, b2, counts, slots, Hbuf, I_CONST);
  // shared up-proj: Hs = silu((x@sw1+sb1)*(x@sw2+sb2))
  up_proj<false><<<dim3(SI_CONST / 64, T_CONST / 64, 1), 256, 0, stream>>>(
      x, sw1, sw2, sb1, sb2, nullptr, nullptr, Hs, SI_CONST);
  // shared down-proj writes z into out (plain stores)
  down_proj<false><<<dim3(D_CONST / 64, T_CONST / 64, 1), 256, 0, stream>>>(
      Hs, sw3, sb3, nullptr, nullptr, nullptr, out, SI_CONST);
  // routed down-proj atomic-adds gate*(H@W3+b3) into out
  down_proj<true><<<dim3(D_CONST / 64, T_CONST / 64, E_CONST), 256, 0, stream>>>(
      Hbuf, W3, b3, counts, slots, gatel, out, I_CONST);
}

// Round 2
// 545.430 us; speedup vs baseline: 2.0182x; 2.0182x over previous
//
#include <hip/hip_runtime.h>
#include <hip/hip_bf16.h>
#include <math.h>

#define T_CONST 2048
#define D_CONST 1024
#define I_CONST 512
#define SI_CONST 1024
#define E_CONST 32
#define G_CONST 8
#define LG_CONST 4
#define KSEL 6

#define BM 128
#define BN 64
#define BK 32

typedef __attribute__((ext_vector_type(8))) short short8;
typedef __attribute__((ext_vector_type(4))) float floatx4;

__device__ inline unsigned pack_bf16(float a, float b) {
  __hip_bfloat162 h = __float22bfloat162_rn(float2{a, b});
  return *reinterpret_cast<unsigned*>(&h);
}

// ---------------- Router ----------------
__global__ __launch_bounds__(256) void router_kernel(
    const float* __restrict__ x, const float* __restrict__ rw,
    const float* __restrict__ rb, int* __restrict__ counts,
    int* __restrict__ slots, float* __restrict__ gatel) {
  int t = blockIdx.x;
  __shared__ float sx[D_CONST];
  __shared__ float slog[E_CONST];
  int tid = threadIdx.x;
  for (int i = tid; i < D_CONST; i += 256) sx[i] = x[(size_t)t * D_CONST + i];
  __syncthreads();
  int e = tid >> 3, l8 = tid & 7;
  float s = 0.f;
  const float* rwp = rw + (size_t)e * D_CONST;
  for (int d = l8; d < D_CONST; d += 8) s += sx[d] * rwp[d];
  s += __shfl_xor(s, 4, 8);
  s += __shfl_xor(s, 2, 8);
  s += __shfl_xor(s, 1, 8);
  if (l8 == 0) slog[e] = s + rb[e];
  __syncthreads();
  if (tid == 0) {
    float sc[E_CONST];
    float mx = -1e30f;
    for (int i = 0; i < E_CONST; ++i) mx = fmaxf(mx, slog[i]);
    float sum = 0.f;
    for (int i = 0; i < E_CONST; ++i) { sc[i] = expf(slog[i] - mx); sum += sc[i]; }
    float inv = 1.f / sum;
    for (int i = 0; i < E_CONST; ++i) sc[i] *= inv;
    float gs[G_CONST];
    for (int g = 0; g < G_CONST; ++g) {
      float m1 = -1e30f, m2 = -1e30f;
      for (int j = 0; j < 4; ++j) {
        float v = sc[g * 4 + j];
        if (v > m1) { m2 = m1; m1 = v; }
        else if (v > m2) { m2 = v; }
      }
      gs[g] = m1 + m2;
    }
    bool keep[G_CONST];
    for (int g = 0; g < G_CONST; ++g) keep[g] = false;
    for (int r = 0; r < LG_CONST; ++r) {
      int bi = -1; float bv = -1e30f;
      for (int g = 0; g < G_CONST; ++g)
        if (!keep[g] && gs[g] > bv) { bv = gs[g]; bi = g; }
      keep[bi] = true;
    }
    bool taken[E_CONST];
    for (int i = 0; i < E_CONST; ++i) taken[i] = false;
    for (int r = 0; r < KSEL; ++r) {
      int bi = -1; float bv = -1e30f;
      for (int i = 0; i < E_CONST; ++i)
        if (keep[i >> 2] && !taken[i] && sc[i] > bv) { bv = sc[i]; bi = i; }
      taken[bi] = true;
      int pos = atomicAdd(&counts[bi], 1);
      slots[bi * T_CONST + pos] = t * KSEL + r;
      gatel[bi * T_CONST + pos] = sc[bi];
    }
  }
}

// ---------------- Fused up-projection (MFMA bf16) ----------------
// H[dst[m]][n] = silu((X@W1+b1)*(X@W2+b2)), on-the-fly fp32->bf16 staging.
template <bool GATHER>
__global__ __launch_bounds__(256, 2) void up_proj_mfma(
    const float* __restrict__ X, const float* __restrict__ W1g,
    const float* __restrict__ W2g, const float* __restrict__ bias1,
    const float* __restrict__ bias2, const int* __restrict__ counts,
    const int* __restrict__ slots, __hip_bfloat16* __restrict__ Hout, int N) {
  const int e = GATHER ? blockIdx.z : 0;
  const int cnt = GATHER ? counts[e] : T_CONST;
  const int m0 = blockIdx.y * BM;
  if (m0 >= cnt) return;
  const int n0 = blockIdx.x * BN;

  // chunk-major LDS: [kchunk(4)][row][8 bf16] -> frag reads are ds_read_b128
  __shared__ short As[4 * BM * 8];
  __shared__ short Bs1[4 * BN * 8];
  __shared__ short Bs2[4 * BN * 8];
  __shared__ int srow[BM];
  __shared__ int sdst[BM];

  const int tid = threadIdx.x;
  for (int i = tid; i < BM; i += 256) {
    int r = m0 + i;
    bool valid = r < cnt;
    if (GATHER) {
      int sl = valid ? slots[e * T_CONST + r] : 0;
      srow[i] = valid ? sl / KSEL : 0;
      sdst[i] = valid ? sl : -1;
    } else {
      srow[i] = valid ? r : 0;
      sdst[i] = valid ? r : -1;
    }
  }
  __syncthreads();

  const float* Wp1 = W1g + (size_t)e * D_CONST * N;
  const float* Wp2 = W2g + (size_t)e * D_CONST * N;

  const int lane = tid & 63;
  const int wave = tid >> 6;
  const int wm = wave & 1, wn = wave >> 1;
  const int l15 = lane & 15, quad = lane >> 4;

  floatx4 acc1[4][2] = {};
  floatx4 acc2[4][2] = {};

  // A staging: item = tid + 256*it ; m = item>>3, kq = tid&7 (4 k each)
  const int akq = tid & 7;
  const float* aptr[4];
#pragma unroll
  for (int it = 0; it < 4; ++it) {
    int m = (tid >> 3) + 32 * it;
    aptr[it] = X + (size_t)srow[m] * D_CONST + akq * 4;
  }
  // B staging: kp = tid>>4 (k pair), nq = tid&15 (4 n each)
  const int bkp = tid >> 4, bnq = tid & 15;
  const int bc = bkp >> 2, bj = (bkp & 3) * 2;

  for (int kk = 0; kk < D_CONST; kk += BK) {
    // ---- stage A (gathered rows, fp32 -> bf16) ----
#pragma unroll
    for (int it = 0; it < 4; ++it) {
      int m = (tid >> 3) + 32 * it;
      float4 f = *(const float4*)(aptr[it] + kk);
      uint2 u;
      u.x = pack_bf16(f.x, f.y);
      u.y = pack_bf16(f.z, f.w);
      int c = akq >> 1, h = akq & 1;
      *(uint2*)&As[(c * BM + m) * 8 + h * 4] = u;
    }
    // ---- stage B1/B2 (transpose pairs: LDS[n][k], k contiguous) ----
    {
      int k = kk + bkp * 2;
      int n = n0 + bnq * 4;
      const float* p1 = Wp1 + (size_t)k * N + n;
      const float* p2 = Wp2 + (size_t)k * N + n;
      float4 r0 = *(const float4*)p1;
      float4 r1 = *(const float4*)(p1 + N);
      float4 q0 = *(const float4*)p2;
      float4 q1 = *(const float4*)(p2 + N);
      int nb = bnq * 4;
      *(unsigned*)&Bs1[(bc * BN + nb + 0) * 8 + bj] = pack_bf16(r0.x, r1.x);
      *(unsigned*)&Bs1[(bc * BN + nb + 1) * 8 + bj] = pack_bf16(r0.y, r1.y);
      *(unsigned*)&Bs1[(bc * BN + nb + 2) * 8 + bj] = pack_bf16(r0.z, r1.z);
      *(unsigned*)&Bs1[(bc * BN + nb + 3) * 8 + bj] = pack_bf16(r0.w, r1.w);
      *(unsigned*)&Bs2[(bc * BN + nb + 0) * 8 + bj] = pack_bf16(q0.x, q1.x);
      *(unsigned*)&Bs2[(bc * BN + nb + 1) * 8 + bj] = pack_bf16(q0.y, q1.y);
      *(unsigned*)&Bs2[(bc * BN + nb + 2) * 8 + bj] = pack_bf16(q0.z, q1.z);
      *(unsigned*)&Bs2[(bc * BN + nb + 3) * 8 + bj] = pack_bf16(q0.w, q1.w);
    }
    __syncthreads();

    short8 a[4];
#pragma unroll
    for (int mi = 0; mi < 4; ++mi)
      a[mi] = *(const short8*)&As[(quad * BM + wm * 64 + mi * 16 + l15) * 8];
#pragma unroll
    for (int ni = 0; ni < 2; ++ni) {
      short8 b1 = *(const short8*)&Bs1[(quad * BN + wn * 32 + ni * 16 + l15) * 8];
      short8 b2 = *(const short8*)&Bs2[(quad * BN + wn * 32 + ni * 16 + l15) * 8];
#pragma unroll
      for (int mi = 0; mi < 4; ++mi) {
        acc1[mi][ni] = __builtin_amdgcn_mfma_f32_16x16x32_bf16(a[mi], b1, acc1[mi][ni], 0, 0, 0);
        acc2[mi][ni] = __builtin_amdgcn_mfma_f32_16x16x32_bf16(a[mi], b2, acc2[mi][ni], 0, 0, 0);
      }
    }
    __syncthreads();
  }

  const float* bb1 = bias1 + (size_t)e * N + n0;
  const float* bb2 = bias2 + (size_t)e * N + n0;
#pragma unroll
  for (int mi = 0; mi < 4; ++mi) {
#pragma unroll
    for (int ni = 0; ni < 2; ++ni) {
      int n = wn * 32 + ni * 16 + l15;
      float c1 = bb1[n], c2 = bb2[n];
#pragma unroll
      for (int reg = 0; reg < 4; ++reg) {
        int row = wm * 64 + mi * 16 + quad * 4 + reg;
        int dst = sdst[row];
        if (dst < 0) continue;
        float h1 = acc1[mi][ni][reg] + c1;
        float h2 = acc2[mi][ni][reg] + c2;
        float p = h1 * h2;
        float s = p / (1.f + expf(-p));
        Hout[(size_t)dst * N + n0 + n] = __float2bfloat16(s);
      }
    }
  }
}

// ---------------- Down projection (MFMA bf16) ----------------
// ROUTED: Out[tok][n] += gate * (H@W3[e] + b3[e])  (atomic)
// else:   Out[tok][n]  = Hs@sw3 + sb3              (plain store, runs first)
template <bool ROUTED>
__global__ __launch_bounds__(256, 2) void down_proj_mfma(
    const __hip_bfloat16* __restrict__ Hin, const float* __restrict__ Wd,
    const float* __restrict__ bd, const int* __restrict__ counts,
    const int* __restrict__ slots, const float* __restrict__ gatel,
    float* __restrict__ Out, int Kdim) {
  const int e = ROUTED ? blockIdx.z : 0;
  const int cnt = ROUTED ? counts[e] : T_CONST;
  const int m0 = blockIdx.y * BM;
  if (m0 >= cnt) return;
  const int n0 = blockIdx.x * BN;

  __shared__ short As[4 * BM * 8];
  __shared__ short Bs[4 * BN * 8];
  __shared__ int ssrc[BM];
  __shared__ int stok[BM];
  __shared__ float sg[BM];

  const int tid = threadIdx.x;
  for (int i = tid; i < BM; i += 256) {
    int r = m0 + i;
    bool valid = r < cnt;
    if (ROUTED) {
      int sl = valid ? slots[e * T_CONST + r] : 0;
      ssrc[i] = sl;
      stok[i] = valid ? (sl / KSEL) : -1;
      sg[i] = valid ? gatel[e * T_CONST + r] : 0.f;
    } else {
      ssrc[i] = valid ? r : 0;
      stok[i] = valid ? r : -1;
      sg[i] = 1.f;
    }
  }
  __syncthreads();

  const float* Wp = Wd + (size_t)e * Kdim * D_CONST;

  const int lane = tid & 63;
  const int wave = tid >> 6;
  const int wm = wave & 1, wn = wave >> 1;
  const int l15 = lane & 15, quad = lane >> 4;

  floatx4 acc[4][2] = {};

  // A staging (bf16 copy): item = tid + 256*it; m = item>>2, ko = tid&3
  const int ako = tid & 3;
  const __hip_bfloat16* aptr[2];
#pragma unroll
  for (int it = 0; it < 2; ++it) {
    int m = (tid >> 2) + 64 * it;
    aptr[it] = Hin + (size_t)ssrc[m] * Kdim + ako * 8;
  }
  const int bkp = tid >> 4, bnq = tid & 15;
  const int bc = bkp >> 2, bj = (bkp & 3) * 2;

  for (int kk = 0; kk < Kdim; kk += BK) {
    // ---- stage A (already bf16, straight 16B copies) ----
#pragma unroll
    for (int it = 0; it < 2; ++it) {
      int m = (tid >> 2) + 64 * it;
      uint4 v = *(const uint4*)(aptr[it] + kk);
      *(uint4*)&As[(ako * BM + m) * 8] = v;
    }
    // ---- stage B (fp32 W[k][n] -> LDS[n][k] bf16) ----
    {
      int k = kk + bkp * 2;
      int n = n0 + bnq * 4;
      const float* p = Wp + (size_t)k * D_CONST + n;
      float4 r0 = *(const float4*)p;
      float4 r1 = *(const float4*)(p + D_CONST);
      int nb = bnq * 4;
      *(unsigned*)&Bs[(bc * BN + nb + 0) * 8 + bj] = pack_bf16(r0.x, r1.x);
      *(unsigned*)&Bs[(bc * BN + nb + 1) * 8 + bj] = pack_bf16(r0.y, r1.y);
      *(unsigned*)&Bs[(bc * BN + nb + 2) * 8 + bj] = pack_bf16(r0.z, r1.z);
      *(unsigned*)&Bs[(bc * BN + nb + 3) * 8 + bj] = pack_bf16(r0.w, r1.w);
    }
    __syncthreads();

    short8 a[4];
#pragma unroll
    for (int mi = 0; mi < 4; ++mi)
      a[mi] = *(const short8*)&As[(quad * BM + wm * 64 + mi * 16 + l15) * 8];
#pragma unroll
    for (int ni = 0; ni < 2; ++ni) {
      short8 b = *(const short8*)&Bs[(quad * BN + wn * 32 + ni * 16 + l15) * 8];
#pragma unroll
      for (int mi = 0; mi < 4; ++mi)
        acc[mi][ni] = __builtin_amdgcn_mfma_f32_16x16x32_bf16(a[mi], b, acc[mi][ni], 0, 0, 0);
    }
    __syncthreads();
  }

#pragma unroll
  for (int mi = 0; mi < 4; ++mi) {
#pragma unroll
    for (int ni = 0; ni < 2; ++ni) {
      int n = n0 + wn * 32 + ni * 16 + l15;
      float bias = ROUTED ? bd[(size_t)e * D_CONST + n] : bd[n];
#pragma unroll
      for (int reg = 0; reg < 4; ++reg) {
        int row = wm * 64 + mi * 16 + quad * 4 + reg;
        int tok = stok[row];
        if (tok < 0) continue;
        if (ROUTED) {
          float v = sg[row] * (acc[mi][ni][reg] + bias);
          atomicAdd(&Out[(size_t)tok * D_CONST + n], v);
        } else {
          Out[(size_t)tok * D_CONST + n] = acc[mi][ni][reg] + bias;
        }
      }
    }
  }
}

extern "C" void kernel_launch(void* const* d_in, const int* in_sizes, int n_in,
                              void* d_out, int out_size, void* d_ws, size_t ws_size,
                              hipStream_t stream) {
  const float* x   = (const float*)d_in[0];
  const float* rw  = (const float*)d_in[1];
  const float* rb  = (const float*)d_in[2];
  const float* W1  = (const float*)d_in[3];
  const float* b1  = (const float*)d_in[4];
  const float* W2  = (const float*)d_in[5];
  const float* b2  = (const float*)d_in[6];
  const float* W3  = (const float*)d_in[7];
  const float* b3  = (const float*)d_in[8];
  const float* sw1 = (const float*)d_in[9];
  const float* sb1 = (const float*)d_in[10];
  const float* sw2 = (const float*)d_in[11];
  const float* sb2 = (const float*)d_in[12];
  const float* sw3 = (const float*)d_in[13];
  const float* sb3 = (const float*)d_in[14];
  float* out = (float*)d_out;

  char* w = (char*)d_ws;
  int* counts = (int*)w;                                       // 256 B
  int* slots = (int*)(w + 256);                                // E*T*4
  float* gatel = (float*)(w + 256 + E_CONST * T_CONST * 4);    // E*T*4
  __hip_bfloat16* Hbuf = (__hip_bfloat16*)(w + 256 + 2 * E_CONST * T_CONST * 4);
  __hip_bfloat16* Hs = (__hip_bfloat16*)(w + 256 + 2 * E_CONST * T_CONST * 4 +
                                         (size_t)T_CONST * KSEL * I_CONST * 2);

  hipMemsetAsync(counts, 0, E_CONST * sizeof(int), stream);
  router_kernel<<<T_CONST, 256, 0, stream>>>(x, rw, rb, counts, slots, gatel);
  // routed up-proj: H = silu((Xg@W1+b1)*(Xg@W2+b2))  [bf16 out]
  up_proj_mfma<true><<<dim3(I_CONST / BN, T_CONST / BM, E_CONST), 256, 0, stream>>>(
      x, W1, W2, b1, b2, counts, slots, Hbuf, I_CONST);
  // shared up-proj
  up_proj_mfma<false><<<dim3(SI_CONST / BN, T_CONST / BM, 1), 256, 0, stream>>>(
      x, sw1, sw2, sb1, sb2, nullptr, nullptr, Hs, SI_CONST);
  // shared down-proj (plain stores, must precede routed atomics)
  down_proj_mfma<false><<<dim3(D_CONST / BN, T_CONST / BM, 1), 256, 0, stream>>>(
      Hs, sw3, sb3, nullptr, nullptr, nullptr, out, SI_CONST);
  // routed down-proj (atomic add)
  down_proj_mfma<true><<<dim3(D_CONST / BN, T_CONST / BM, E_CONST), 256, 0, stream>>>(
      Hbuf, W3, b3, counts, slots, gatel, out, I_CONST);
}

// Round 3
// 537.656 us; speedup vs baseline: 2.0473x; 1.0145x over previous
//
#include <hip/hip_runtime.h>
#include <hip/hip_bf16.h>
#include <math.h>

#define T_CONST 2048
#define D_CONST 1024
#define I_CONST 512
#define SI_CONST 1024
#define E_CONST 32
#define G_CONST 8
#define LG_CONST 4
#define KSEL 6

#define BM 128
#define BN 64
#define BK 64

typedef __attribute__((ext_vector_type(8))) short short8;
typedef __attribute__((ext_vector_type(4))) float floatx4;

__device__ inline unsigned pack_bf16(float a, float b) {
  __hip_bfloat162 h = __float22bfloat162_rn(float2{a, b});
  return *reinterpret_cast<unsigned*>(&h);
}

// async global->LDS, 16B per lane. LDS dest must be base + lane*16.
__device__ inline void gload16(const void* g, void* l) {
  __builtin_amdgcn_global_load_lds(
      (const __attribute__((address_space(1))) unsigned int*)g,
      (__attribute__((address_space(3))) unsigned int*)l, 16, 0, 0);
}

// ---------------- conversions ----------------
__global__ __launch_bounds__(256) void cvt_x(const float* __restrict__ in,
                                             __hip_bfloat16* __restrict__ out) {
  size_t i = ((size_t)blockIdx.x * 256 + threadIdx.x) * 4;
  float4 v = *(const float4*)&in[i];
  uint2 u{pack_bf16(v.x, v.y), pack_bf16(v.z, v.w)};
  *(uint2*)&out[i] = u;
}

__global__ __launch_bounds__(256) void cvt_rwt(const float* __restrict__ rw,
                                               float* __restrict__ rwt) {
  int i = blockIdx.x * 256 + threadIdx.x;  // 32768 total
  int d = i >> 5, e = i & 31;
  rwt[d * 32 + e] = rw[e * D_CONST + d];
}

// fp32 [K][N] row-major -> bf16 [N][K] (transposed), fused over all weights
__global__ __launch_bounds__(256) void transpose_all(
    const float* __restrict__ W1, const float* __restrict__ W2,
    const float* __restrict__ W3, const float* __restrict__ sw1,
    const float* __restrict__ sw2, const float* __restrict__ sw3,
    __hip_bfloat16* __restrict__ W1t, __hip_bfloat16* __restrict__ W2t,
    __hip_bfloat16* __restrict__ W3t, __hip_bfloat16* __restrict__ sw1t,
    __hip_bfloat16* __restrict__ sw2t, __hip_bfloat16* __restrict__ sw3t) {
  __shared__ float tile[64][65];
  int b = blockIdx.x;
  const float* in;
  __hip_bfloat16* out;
  int K, N, k0, n0;
  if (b < 8192) {  // W1 / W2 : K=1024, N=512, 128 blocks per matrix
    int local = b & 4095;
    int mat = local >> 7, rem = local & 127;
    K = 1024; N = 512;
    in = ((b < 4096) ? W1 : W2) + (size_t)mat * (1024 * 512);
    out = ((b < 4096) ? W1t : W2t) + (size_t)mat * (1024 * 512);
    n0 = (rem & 7) * 64; k0 = (rem >> 3) * 64;
  } else if (b < 12288) {  // W3 : K=512, N=1024
    int local = b - 8192;
    int mat = local >> 7, rem = local & 127;
    K = 512; N = 1024;
    in = W3 + (size_t)mat * (512 * 1024);
    out = W3t + (size_t)mat * (512 * 1024);
    n0 = (rem & 15) * 64; k0 = (rem >> 4) * 64;
  } else {  // sw1/sw2/sw3 : 1024x1024
    int local = b - 12288;
    int which = local >> 8, rem = local & 255;
    K = 1024; N = 1024;
    in = which == 0 ? sw1 : which == 1 ? sw2 : sw3;
    out = which == 0 ? sw1t : which == 1 ? sw2t : sw3t;
    n0 = (rem & 15) * 64; k0 = (rem >> 4) * 64;
  }
  int tid = threadIdx.x;
  int tr = tid >> 4, tc4 = (tid & 15) * 4;
#pragma unroll
  for (int i = 0; i < 4; ++i) {
    float4 v = *(const float4*)&in[(size_t)(k0 + tr + 16 * i) * N + n0 + tc4];
    tile[tr + 16 * i][tc4 + 0] = v.x;
    tile[tr + 16 * i][tc4 + 1] = v.y;
    tile[tr + 16 * i][tc4 + 2] = v.z;
    tile[tr + 16 * i][tc4 + 3] = v.w;
  }
  __syncthreads();
#pragma unroll
  for (int i = 0; i < 4; ++i) {
    int n = tr + 16 * i;
    unsigned lo = pack_bf16(tile[tc4 + 0][n], tile[tc4 + 1][n]);
    unsigned hi = pack_bf16(tile[tc4 + 2][n], tile[tc4 + 3][n]);
    uint2 u{lo, hi};
    *(uint2*)&out[(size_t)(n0 + n) * K + k0 + tc4] = u;
  }
}

// ---------------- Router: one wave per token ----------------
__global__ __launch_bounds__(256) void router2(
    const float* __restrict__ x, const float* __restrict__ rwt,
    const float* __restrict__ rb, int* __restrict__ counts,
    int* __restrict__ slots, float* __restrict__ gatel) {
  const int lane = threadIdx.x & 63;
  const int wv = threadIdx.x >> 6;
  const int t = blockIdx.x * 4 + wv;
  const int e = lane & 31, h = lane >> 5;
  const float* xp = x + (size_t)t * D_CONST;
  float s = 0.f;
#pragma unroll 8
  for (int d = h; d < D_CONST; d += 2) s = fmaf(xp[d], rwt[d * 32 + e], s);
  s += __shfl_xor(s, 32);
  s += rb[e];
  // softmax over 32 experts (duplicated across halves)
  float mx = s;
#pragma unroll
  for (int m = 16; m >= 1; m >>= 1) mx = fmaxf(mx, __shfl_xor(mx, m));
  float p = expf(s - mx);
  float sum = p;
#pragma unroll
  for (int m = 16; m >= 1; m >>= 1) sum += __shfl_xor(sum, m);
  float sc = p / sum;
  // group score = sum of top-2 within group of 4
  float a = sc, bb = __shfl_xor(a, 1);
  float hi = fmaxf(a, bb), lo = fminf(a, bb);
  float oh = __shfl_xor(hi, 2), ol = __shfl_xor(lo, 2);
  float gs = fmaxf(fmaxf(hi + oh, hi + lo), oh + ol);
  const int g = e >> 2;
  // top-4 groups
  unsigned keep = 0;
  float gv = gs;
#pragma unroll
  for (int r = 0; r < LG_CONST; ++r) {
    float v = gv;
    int gi = g;
#pragma unroll
    for (int m = 16; m >= 1; m >>= 1) {
      float ov = __shfl_xor(v, m);
      int og = __shfl_xor(gi, m);
      if (ov > v || (ov == v && og < gi)) { v = ov; gi = og; }
    }
    keep |= 1u << gi;
    if (g == gi) gv = -1e30f;
  }
  // top-6 experts within kept groups
  float cand = ((keep >> g) & 1u) ? sc : -1e30f;
  int sel_e = -1;
  float sel_v = 0.f;
#pragma unroll
  for (int r = 0; r < KSEL; ++r) {
    float v = cand;
    int ei = e;
#pragma unroll
    for (int m = 16; m >= 1; m >>= 1) {
      float ov = __shfl_xor(v, m);
      int oe = __shfl_xor(ei, m);
      if (ov > v || (ov == v && oe < ei)) { v = ov; ei = oe; }
    }
    if (lane == r) { sel_e = ei; sel_v = v; }
    if (e == ei) cand = -1e30f;
  }
  if (lane < KSEL) {
    int pos = atomicAdd(&counts[sel_e], 1);
    slots[sel_e * T_CONST + pos] = t * KSEL + lane;
    gatel[sel_e * T_CONST + pos] = sel_v;
  }
}

// ---------------- Up projection (dual-B MFMA, async staging) ----------------
template <bool GATHER>
__global__ __launch_bounds__(256, 2) void up_mfma2(
    const __hip_bfloat16* __restrict__ Abf, const __hip_bfloat16* __restrict__ B1t,
    const __hip_bfloat16* __restrict__ B2t, const float* __restrict__ bias1,
    const float* __restrict__ bias2, const int* __restrict__ counts,
    const int* __restrict__ slots, __hip_bfloat16* __restrict__ Hout,
    int N, int Kd) {
  const int e = GATHER ? blockIdx.z : 0;
  const int cnt = GATHER ? counts[e] : T_CONST;
  const int m0 = blockIdx.y * BM;
  if (m0 >= cnt) return;
  const int n0 = blockIdx.x * BN;

  __shared__ short As[8 * BM * 8];
  __shared__ short Bs1[8 * BN * 8];
  __shared__ short Bs2[8 * BN * 8];
  __shared__ int srow[BM];
  __shared__ int sdst[BM];

  const int tid = threadIdx.x;
  const int lane = tid & 63, wv = tid >> 6;
  if (tid < BM) {
    int r = m0 + tid;
    bool valid = r < cnt;
    if (GATHER) {
      int sl = valid ? slots[e * T_CONST + r] : 0;
      srow[tid] = valid ? sl / KSEL : 0;
      sdst[tid] = valid ? sl : -1;
    } else {
      srow[tid] = valid ? r : 0;
      sdst[tid] = valid ? r : -1;
    }
  }
  __syncthreads();

  const char* agp[4];
  short* alds[4];
  const char* bgp[4];
  short* blds[4];
  {
    int row0 = srow[lane], row1 = srow[64 + lane];
#pragma unroll
    for (int i = 0; i < 4; ++i) {
      int kc = 2 * wv + (i >> 1);
      int mh = i & 1;
      agp[i] = (const char*)(Abf + (size_t)(mh ? row1 : row0) * Kd + kc * 8);
      alds[i] = (short*)As + (kc * BM + mh * 64 + lane) * 8;
    }
    const __hip_bfloat16* Bsel = (wv < 2 ? B1t : B2t) + (size_t)e * N * Kd;
    short* Lsel = (wv < 2) ? (short*)Bs1 : (short*)Bs2;
    int wl = wv & 1;
#pragma unroll
    for (int i = 0; i < 4; ++i) {
      int kc = wl * 4 + i;
      bgp[i] = (const char*)(Bsel + (size_t)(n0 + lane) * Kd + kc * 8);
      blds[i] = Lsel + (kc * BN + lane) * 8;
    }
  }

  const int l15 = lane & 15, quad = lane >> 4;
  const int wm = wv & 1, wn = wv >> 1;
  floatx4 acc1[4][2] = {};
  floatx4 acc2[4][2] = {};
  const int kiter = Kd / BK;

  for (int it = 0; it < kiter; ++it) {
#pragma unroll
    for (int i = 0; i < 4; ++i) gload16(agp[i], alds[i]);
#pragma unroll
    for (int i = 0; i < 4; ++i) gload16(bgp[i], blds[i]);
#pragma unroll
    for (int i = 0; i < 4; ++i) { agp[i] += BK * 2; bgp[i] += BK * 2; }
    __syncthreads();
    short8 a[2][4];
#pragma unroll
    for (int s = 0; s < 2; ++s)
#pragma unroll
      for (int mi = 0; mi < 4; ++mi)
        a[s][mi] = *(const short8*)&As[((s * 4 + quad) * BM + wm * 64 + mi * 16 + l15) * 8];
#pragma unroll
    for (int s = 0; s < 2; ++s)
#pragma unroll
      for (int ni = 0; ni < 2; ++ni) {
        short8 b1 = *(const short8*)&Bs1[((s * 4 + quad) * BN + wn * 32 + ni * 16 + l15) * 8];
        short8 b2 = *(const short8*)&Bs2[((s * 4 + quad) * BN + wn * 32 + ni * 16 + l15) * 8];
#pragma unroll
        for (int mi = 0; mi < 4; ++mi) {
          acc1[mi][ni] = __builtin_amdgcn_mfma_f32_16x16x32_bf16(a[s][mi], b1, acc1[mi][ni], 0, 0, 0);
          acc2[mi][ni] = __builtin_amdgcn_mfma_f32_16x16x32_bf16(a[s][mi], b2, acc2[mi][ni], 0, 0, 0);
        }
      }
    __syncthreads();
  }

  const float* bb1 = bias1 + (size_t)e * N + n0;
  const float* bb2 = bias2 + (size_t)e * N + n0;
#pragma unroll
  for (int mi = 0; mi < 4; ++mi) {
#pragma unroll
    for (int ni = 0; ni < 2; ++ni) {
      int n = wn * 32 + ni * 16 + l15;
      float c1 = bb1[n], c2 = bb2[n];
#pragma unroll
      for (int reg = 0; reg < 4; ++reg) {
        int row = wm * 64 + mi * 16 + quad * 4 + reg;
        int dst = sdst[row];
        if (dst < 0) continue;
        float h1 = acc1[mi][ni][reg] + c1;
        float h2 = acc2[mi][ni][reg] + c2;
        float p = h1 * h2;
        float sv = p / (1.f + expf(-p));
        Hout[(size_t)dst * N + n0 + n] = __float2bfloat16(sv);
      }
    }
  }
}

// ---------------- Down projection (single-B MFMA, async staging) ----------------
template <bool ROUTED>
__global__ __launch_bounds__(256, 2) void down_mfma2(
    const __hip_bfloat16* __restrict__ Hin, const __hip_bfloat16* __restrict__ Bt,
    const float* __restrict__ bd, const int* __restrict__ counts,
    const int* __restrict__ slots, const float* __restrict__ gatel,
    float* __restrict__ Out, int Kd) {
  const int e = ROUTED ? blockIdx.z : 0;
  const int cnt = ROUTED ? counts[e] : T_CONST;
  const int m0 = blockIdx.y * BM;
  if (m0 >= cnt) return;
  const int n0 = blockIdx.x * BN;

  __shared__ short As[8 * BM * 8];
  __shared__ short Bs[8 * BN * 8];
  __shared__ int ssrc[BM];
  __shared__ int stok[BM];
  __shared__ float sg[BM];

  const int tid = threadIdx.x;
  const int lane = tid & 63, wv = tid >> 6;
  if (tid < BM) {
    int r = m0 + tid;
    bool valid = r < cnt;
    if (ROUTED) {
      int sl = valid ? slots[e * T_CONST + r] : 0;
      ssrc[tid] = sl;
      stok[tid] = valid ? (sl / KSEL) : -1;
      sg[tid] = valid ? gatel[e * T_CONST + r] : 0.f;
    } else {
      ssrc[tid] = valid ? r : 0;
      stok[tid] = valid ? r : -1;
      sg[tid] = 1.f;
    }
  }
  __syncthreads();

  const char* agp[4];
  short* alds[4];
  const char* bgp[2];
  short* blds[2];
  {
    int row0 = ssrc[lane], row1 = ssrc[64 + lane];
#pragma unroll
    for (int i = 0; i < 4; ++i) {
      int kc = 2 * wv + (i >> 1);
      int mh = i & 1;
      agp[i] = (const char*)(Hin + (size_t)(mh ? row1 : row0) * Kd + kc * 8);
      alds[i] = (short*)As + (kc * BM + mh * 64 + lane) * 8;
    }
    const __hip_bfloat16* Bsel = Bt + (size_t)e * D_CONST * Kd;
#pragma unroll
    for (int i = 0; i < 2; ++i) {
      int kc = 2 * wv + i;
      bgp[i] = (const char*)(Bsel + (size_t)(n0 + lane) * Kd + kc * 8);
      blds[i] = (short*)Bs + (kc * BN + lane) * 8;
    }
  }

  const int l15 = lane & 15, quad = lane >> 4;
  const int wm = wv & 1, wn = wv >> 1;
  floatx4 acc[4][2] = {};
  const int kiter = Kd / BK;

  for (int it = 0; it < kiter; ++it) {
#pragma unroll
    for (int i = 0; i < 4; ++i) gload16(agp[i], alds[i]);
#pragma unroll
    for (int i = 0; i < 2; ++i) gload16(bgp[i], blds[i]);
#pragma unroll
    for (int i = 0; i < 4; ++i) agp[i] += BK * 2;
#pragma unroll
    for (int i = 0; i < 2; ++i) bgp[i] += BK * 2;
    __syncthreads();
    short8 a[2][4];
#pragma unroll
    for (int s = 0; s < 2; ++s)
#pragma unroll
      for (int mi = 0; mi < 4; ++mi)
        a[s][mi] = *(const short8*)&As[((s * 4 + quad) * BM + wm * 64 + mi * 16 + l15) * 8];
#pragma unroll
    for (int s = 0; s < 2; ++s)
#pragma unroll
      for (int ni = 0; ni < 2; ++ni) {
        short8 b = *(const short8*)&Bs[((s * 4 + quad) * BN + wn * 32 + ni * 16 + l15) * 8];
#pragma unroll
        for (int mi = 0; mi < 4; ++mi)
          acc[mi][ni] = __builtin_amdgcn_mfma_f32_16x16x32_bf16(a[s][mi], b, acc[mi][ni], 0, 0, 0);
      }
    __syncthreads();
  }

#pragma unroll
  for (int mi = 0; mi < 4; ++mi) {
#pragma unroll
    for (int ni = 0; ni < 2; ++ni) {
      int n = n0 + wn * 32 + ni * 16 + l15;
      float bias = ROUTED ? bd[(size_t)e * D_CONST + n] : bd[n];
#pragma unroll
      for (int reg = 0; reg < 4; ++reg) {
        int row = wm * 64 + mi * 16 + quad * 4 + reg;
        int tok = stok[row];
        if (tok < 0) continue;
        if (ROUTED) {
          float v = sg[row] * (acc[mi][ni][reg] + bias);
          atomicAdd(&Out[(size_t)tok * D_CONST + n], v);
        } else {
          Out[(size_t)tok * D_CONST + n] = acc[mi][ni][reg] + bias;
        }
      }
    }
  }
}

extern "C" void kernel_launch(void* const* d_in, const int* in_sizes, int n_in,
                              void* d_out, int out_size, void* d_ws, size_t ws_size,
                              hipStream_t stream) {
  const float* x   = (const float*)d_in[0];
  const float* rw  = (const float*)d_in[1];
  const float* rb  = (const float*)d_in[2];
  const float* W1  = (const float*)d_in[3];
  const float* b1  = (const float*)d_in[4];
  const float* W2  = (const float*)d_in[5];
  const float* b2  = (const float*)d_in[6];
  const float* W3  = (const float*)d_in[7];
  const float* b3  = (const float*)d_in[8];
  const float* sw1 = (const float*)d_in[9];
  const float* sb1 = (const float*)d_in[10];
  const float* sw2 = (const float*)d_in[11];
  const float* sb2 = (const float*)d_in[12];
  const float* sw3 = (const float*)d_in[13];
  const float* sb3 = (const float*)d_in[14];
  float* out = (float*)d_out;

  char* w = (char*)d_ws;
  size_t off = 0;
  auto alloc = [&](size_t bytes) {
    char* p = w + off;
    off += (bytes + 255) & ~(size_t)255;
    return p;
  };
  int* counts = (int*)alloc(E_CONST * 4);
  int* slots = (int*)alloc((size_t)E_CONST * T_CONST * 4);
  float* gatel = (float*)alloc((size_t)E_CONST * T_CONST * 4);
  float* rwt = (float*)alloc((size_t)D_CONST * E_CONST * 4);
  __hip_bfloat16* x_bf = (__hip_bfloat16*)alloc((size_t)T_CONST * D_CONST * 2);
  __hip_bfloat16* W1t = (__hip_bfloat16*)alloc((size_t)E_CONST * D_CONST * I_CONST * 2);
  __hip_bfloat16* W2t = (__hip_bfloat16*)alloc((size_t)E_CONST * D_CONST * I_CONST * 2);
  __hip_bfloat16* W3t = (__hip_bfloat16*)alloc((size_t)E_CONST * I_CONST * D_CONST * 2);
  __hip_bfloat16* sw1t = (__hip_bfloat16*)alloc((size_t)D_CONST * SI_CONST * 2);
  __hip_bfloat16* sw2t = (__hip_bfloat16*)alloc((size_t)D_CONST * SI_CONST * 2);
  __hip_bfloat16* sw3t = (__hip_bfloat16*)alloc((size_t)SI_CONST * D_CONST * 2);
  __hip_bfloat16* Hbuf = (__hip_bfloat16*)alloc((size_t)T_CONST * KSEL * I_CONST * 2);
  __hip_bfloat16* Hs = (__hip_bfloat16*)alloc((size_t)T_CONST * SI_CONST * 2);

  hipMemsetAsync(counts, 0, E_CONST * sizeof(int), stream);
  cvt_rwt<<<(D_CONST * E_CONST) / 256, 256, 0, stream>>>(rw, rwt);
  cvt_x<<<(T_CONST * D_CONST) / 1024, 256, 0, stream>>>(x, x_bf);
  transpose_all<<<13056, 256, 0, stream>>>(W1, W2, W3, sw1, sw2, sw3,
                                           W1t, W2t, W3t, sw1t, sw2t, sw3t);
  router2<<<T_CONST / 4, 256, 0, stream>>>(x, rwt, rb, counts, slots, gatel);
  // routed up-proj: Hbuf = silu((Xg@W1+b1)*(Xg@W2+b2))
  up_mfma2<true><<<dim3(I_CONST / BN, T_CONST / BM, E_CONST), 256, 0, stream>>>(
      x_bf, W1t, W2t, b1, b2, counts, slots, Hbuf, I_CONST, D_CONST);
  // shared up-proj
  up_mfma2<false><<<dim3(SI_CONST / BN, T_CONST / BM, 1), 256, 0, stream>>>(
      x_bf, sw1t, sw2t, sb1, sb2, nullptr, nullptr, Hs, SI_CONST, D_CONST);
  // shared down-proj (plain stores; must precede routed atomics)
  down_mfma2<false><<<dim3(D_CONST / BN, T_CONST / BM, 1), 256, 0, stream>>>(
      Hs, sw3t, sb3, nullptr, nullptr, nullptr, out, SI_CONST);
  // routed down-proj (atomic add of gate*(H@W3+b3))
  down_mfma2<true><<<dim3(D_CONST / BN, T_CONST / BM, E_CONST), 256, 0, stream>>>(
      Hbuf, W3t, b3, counts, slots, gatel, out, I_CONST);
}

// Round 4
// 506.333 us; speedup vs baseline: 2.1740x; 1.0619x over previous
//
#include <hip/hip_runtime.h>
#include <hip/hip_bf16.h>
#include <math.h>

#define T_CONST 2048
#define D_CONST 1024
#define I_CONST 512
#define SI_CONST 1024
#define E_CONST 32
#define G_CONST 8
#define LG_CONST 4
#define KSEL 6

typedef __attribute__((ext_vector_type(8))) short short8;
typedef __attribute__((ext_vector_type(4))) float floatx4;

__device__ inline unsigned pack_bf16(float a, float b) {
  __hip_bfloat162 h = __float22bfloat162_rn(float2{a, b});
  return *reinterpret_cast<unsigned*>(&h);
}

// async global->LDS, 16B per lane; LDS dest must be base + lane*16.
__device__ inline void gload16(const void* g, void* l) {
  __builtin_amdgcn_global_load_lds(
      (const __attribute__((address_space(1))) unsigned int*)g,
      (__attribute__((address_space(3))) unsigned int*)l, 16, 0, 0);
}

// ---------------- conversions ----------------
__global__ __launch_bounds__(256) void cvt_x(const float* __restrict__ in,
                                             __hip_bfloat16* __restrict__ out) {
  size_t i = ((size_t)blockIdx.x * 256 + threadIdx.x) * 4;
  float4 v = *(const float4*)&in[i];
  uint2 u{pack_bf16(v.x, v.y), pack_bf16(v.z, v.w)};
  *(uint2*)&out[i] = u;
}

__global__ __launch_bounds__(256) void cvt_rwt(const float* __restrict__ rw,
                                               float* __restrict__ rwt) {
  int i = blockIdx.x * 256 + threadIdx.x;  // 32768 total
  int d = i >> 5, e = i & 31;
  rwt[d * 32 + e] = rw[e * D_CONST + d];
}

// fp32 [K][N] row-major -> bf16 [N][K] (transposed), fused over all weights
__global__ __launch_bounds__(256) void transpose_all(
    const float* __restrict__ W1, const float* __restrict__ W2,
    const float* __restrict__ W3, const float* __restrict__ sw1,
    const float* __restrict__ sw2, const float* __restrict__ sw3,
    __hip_bfloat16* __restrict__ W1t, __hip_bfloat16* __restrict__ W2t,
    __hip_bfloat16* __restrict__ W3t, __hip_bfloat16* __restrict__ sw1t,
    __hip_bfloat16* __restrict__ sw2t, __hip_bfloat16* __restrict__ sw3t) {
  __shared__ float tile[64][65];
  int b = blockIdx.x;
  const float* in;
  __hip_bfloat16* out;
  int K, N, k0, n0;
  if (b < 8192) {  // W1 / W2 : K=1024, N=512, 128 blocks per matrix
    int local = b & 4095;
    int mat = local >> 7, rem = local & 127;
    K = 1024; N = 512;
    in = ((b < 4096) ? W1 : W2) + (size_t)mat * (1024 * 512);
    out = ((b < 4096) ? W1t : W2t) + (size_t)mat * (1024 * 512);
    n0 = (rem & 7) * 64; k0 = (rem >> 3) * 64;
  } else if (b < 12288) {  // W3 : K=512, N=1024
    int local = b - 8192;
    int mat = local >> 7, rem = local & 127;
    K = 512; N = 1024;
    in = W3 + (size_t)mat * (512 * 1024);
    out = W3t + (size_t)mat * (512 * 1024);
    n0 = (rem & 15) * 64; k0 = (rem >> 4) * 64;
  } else {  // sw1/sw2/sw3 : 1024x1024
    int local = b - 12288;
    int which = local >> 8, rem = local & 255;
    K = 1024; N = 1024;
    in = which == 0 ? sw1 : which == 1 ? sw2 : sw3;
    out = which == 0 ? sw1t : which == 1 ? sw2t : sw3t;
    n0 = (rem & 15) * 64; k0 = (rem >> 4) * 64;
  }
  int tid = threadIdx.x;
  int tr = tid >> 4, tc4 = (tid & 15) * 4;
#pragma unroll
  for (int i = 0; i < 4; ++i) {
    float4 v = *(const float4*)&in[(size_t)(k0 + tr + 16 * i) * N + n0 + tc4];
    tile[tr + 16 * i][tc4 + 0] = v.x;
    tile[tr + 16 * i][tc4 + 1] = v.y;
    tile[tr + 16 * i][tc4 + 2] = v.z;
    tile[tr + 16 * i][tc4 + 3] = v.w;
  }
  __syncthreads();
#pragma unroll
  for (int i = 0; i < 4; ++i) {
    int n = tr + 16 * i;
    unsigned lo = pack_bf16(tile[tc4 + 0][n], tile[tc4 + 1][n]);
    unsigned hi = pack_bf16(tile[tc4 + 2][n], tile[tc4 + 3][n]);
    uint2 u{lo, hi};
    *(uint2*)&out[(size_t)(n0 + n) * K + k0 + tc4] = u;
  }
}

// ---------------- Router: one wave per token ----------------
__global__ __launch_bounds__(256) void router2(
    const float* __restrict__ x, const float* __restrict__ rwt,
    const float* __restrict__ rb, int* __restrict__ counts,
    int* __restrict__ stok, float* __restrict__ gatel) {
  const int lane = threadIdx.x & 63;
  const int wv = threadIdx.x >> 6;
  const int t = blockIdx.x * 4 + wv;
  const int e = lane & 31, h = lane >> 5;
  const float* xp = x + (size_t)t * D_CONST;
  float s = 0.f;
#pragma unroll 8
  for (int d = h; d < D_CONST; d += 2) s = fmaf(xp[d], rwt[d * 32 + e], s);
  s += __shfl_xor(s, 32);
  s += rb[e];
  float mx = s;
#pragma unroll
  for (int m = 16; m >= 1; m >>= 1) mx = fmaxf(mx, __shfl_xor(mx, m));
  float p = expf(s - mx);
  float sum = p;
#pragma unroll
  for (int m = 16; m >= 1; m >>= 1) sum += __shfl_xor(sum, m);
  float sc = p / sum;
  float a = sc, bb = __shfl_xor(a, 1);
  float hi = fmaxf(a, bb), lo = fminf(a, bb);
  float oh = __shfl_xor(hi, 2), ol = __shfl_xor(lo, 2);
  float gs = fmaxf(fmaxf(hi + oh, hi + lo), oh + ol);
  const int g = e >> 2;
  unsigned keep = 0;
  float gv = gs;
#pragma unroll
  for (int r = 0; r < LG_CONST; ++r) {
    float v = gv;
    int gi = g;
#pragma unroll
    for (int m = 16; m >= 1; m >>= 1) {
      float ov = __shfl_xor(v, m);
      int og = __shfl_xor(gi, m);
      if (ov > v || (ov == v && og < gi)) { v = ov; gi = og; }
    }
    keep |= 1u << gi;
    if (g == gi) gv = -1e30f;
  }
  float cand = ((keep >> g) & 1u) ? sc : -1e30f;
  int sel_e = -1;
  float sel_v = 0.f;
#pragma unroll
  for (int r = 0; r < KSEL; ++r) {
    float v = cand;
    int ei = e;
#pragma unroll
    for (int m = 16; m >= 1; m >>= 1) {
      float ov = __shfl_xor(v, m);
      int oe = __shfl_xor(ei, m);
      if (ov > v || (ov == v && oe < ei)) { v = ov; ei = oe; }
    }
    if (lane == r) { sel_e = ei; sel_v = v; }
    if (e == ei) cand = -1e30f;
  }
  if (lane < KSEL) {
    int pos = atomicAdd(&counts[sel_e], 1);
    stok[sel_e * T_CONST + pos] = t;
    gatel[sel_e * T_CONST + pos] = sel_v;
  }
}

// ---------------- prefix sum of expert counts ----------------
__global__ void scan_k(const int* __restrict__ counts, int* __restrict__ offsets) {
  if (threadIdx.x == 0) {
    int s = 0;
    for (int e = 0; e < E_CONST; ++e) { offsets[e] = s; s += counts[e]; }
    offsets[E_CONST] = s;
  }
}

// ---------------- gather tokens into expert-packed Xg ----------------
__global__ __launch_bounds__(256) void gather_x(
    const __hip_bfloat16* __restrict__ xbf, const int* __restrict__ counts,
    const int* __restrict__ offsets, const int* __restrict__ stok,
    const float* __restrict__ gatel, __hip_bfloat16* __restrict__ Xg,
    int* __restrict__ ctok, float* __restrict__ cgate) {
  int e = blockIdx.x;
  int cnt = counts[e];
  int row = blockIdx.y * 16 + (threadIdx.x >> 4);
  if (row >= cnt) return;
  int seg = threadIdx.x & 15;
  int tok = stok[e * T_CONST + row];
  int dst = offsets[e] + row;
  const uint4* src = (const uint4*)(xbf + (size_t)tok * D_CONST);
  uint4* d = (uint4*)(Xg + (size_t)dst * D_CONST);
#pragma unroll
  for (int i = 0; i < 8; ++i) d[i * 16 + seg] = src[i * 16 + seg];
  if (seg == 0) { ctok[dst] = tok; cgate[dst] = gatel[e * T_CONST + row]; }
}

// ---------------- Fused up-projection (routed z<32, shared z==32) ----------
// XOR-swizzled LDS: logical (row r, kchunk kc) lives at 16B-unit r*8+(kc^(r&7)).
__global__ __launch_bounds__(256, 2) void up_fused(
    const __hip_bfloat16* __restrict__ Xg, const __hip_bfloat16* __restrict__ xbf,
    const __hip_bfloat16* __restrict__ W1t, const __hip_bfloat16* __restrict__ W2t,
    const __hip_bfloat16* __restrict__ sw1t, const __hip_bfloat16* __restrict__ sw2t,
    const float* __restrict__ b1, const float* __restrict__ b2,
    const float* __restrict__ sb1, const float* __restrict__ sb2,
    const int* __restrict__ counts, const int* __restrict__ offsets,
    __hip_bfloat16* __restrict__ He, __hip_bfloat16* __restrict__ Hs) {
  const int z = blockIdx.z;
  const bool SH = (z == E_CONST);
  const int N = SH ? SI_CONST : I_CONST;
  const int n0 = blockIdx.x * 128;
  if (n0 >= N) return;
  const int cnt = SH ? T_CONST : counts[z];
  const int m0 = blockIdx.y * 128;
  if (m0 >= cnt) return;
  const int base = SH ? 0 : offsets[z];

  const __hip_bfloat16* Ab = SH ? (xbf + (size_t)m0 * D_CONST)
                                : (Xg + (size_t)(base + m0) * D_CONST);
  const __hip_bfloat16* B1 = SH ? (sw1t + (size_t)n0 * D_CONST)
                                : (W1t + ((size_t)z * I_CONST + n0) * D_CONST);
  const __hip_bfloat16* B2 = SH ? (sw2t + (size_t)n0 * D_CONST)
                                : (W2t + ((size_t)z * I_CONST + n0) * D_CONST);

  __shared__ short As[8192], Bs1[8192], Bs2[8192];

  const int tid = threadIdx.x, lane = tid & 63, wv = tid >> 6;
  const int l15 = lane & 15, quad = lane >> 4;
  const int wm = wv & 1, wn = wv >> 1;
  const int lr = lane >> 3, lc = lane & 7, kap = lc ^ lr;

  const __hip_bfloat16 *aG[4], *b1G[4], *b2G[4];
#pragma unroll
  for (int i = 0; i < 4; ++i) {
    int r = (wv * 4 + i) * 8 + lr;
    aG[i] = Ab + (size_t)r * D_CONST + kap * 8;
    b1G[i] = B1 + (size_t)r * D_CONST + kap * 8;
    b2G[i] = B2 + (size_t)r * D_CONST + kap * 8;
  }
  const int ldsu = (wv * 4 * 64 + lane) * 8;

  floatx4 acc1[4][4] = {};
  floatx4 acc2[4][4] = {};

  for (int it = 0; it < D_CONST / 64; ++it) {
#pragma unroll
    for (int i = 0; i < 4; ++i) {
      gload16(aG[i], &As[ldsu + i * 512]);
      gload16(b1G[i], &Bs1[ldsu + i * 512]);
      gload16(b2G[i], &Bs2[ldsu + i * 512]);
      aG[i] += 64; b1G[i] += 64; b2G[i] += 64;
    }
    __syncthreads();
#pragma unroll
    for (int c = 0; c < 2; ++c) {
      const int kc = c * 4 + quad;
      short8 a[4], x1[4], x2[4];
#pragma unroll
      for (int mi = 0; mi < 4; ++mi) {
        int m = wm * 64 + mi * 16 + l15;
        a[mi] = *(const short8*)&As[(m * 8 + (kc ^ (m & 7))) * 8];
      }
#pragma unroll
      for (int ni = 0; ni < 4; ++ni) {
        int n = wn * 64 + ni * 16 + l15;
        int u = (n * 8 + (kc ^ (n & 7))) * 8;
        x1[ni] = *(const short8*)&Bs1[u];
        x2[ni] = *(const short8*)&Bs2[u];
      }
#pragma unroll
      for (int mi = 0; mi < 4; ++mi)
#pragma unroll
        for (int ni = 0; ni < 4; ++ni) {
          acc1[mi][ni] = __builtin_amdgcn_mfma_f32_16x16x32_bf16(a[mi], x1[ni], acc1[mi][ni], 0, 0, 0);
          acc2[mi][ni] = __builtin_amdgcn_mfma_f32_16x16x32_bf16(a[mi], x2[ni], acc2[mi][ni], 0, 0, 0);
        }
    }
    __syncthreads();
  }

  const float* pb1 = SH ? sb1 : (b1 + (size_t)z * I_CONST);
  const float* pb2 = SH ? sb2 : (b2 + (size_t)z * I_CONST);
  __hip_bfloat16* outp = SH ? (Hs + (size_t)m0 * SI_CONST + n0)
                            : (He + (size_t)(base + m0) * I_CONST + n0);
  const int ldo = SH ? SI_CONST : I_CONST;
  float c1[4], c2[4];
#pragma unroll
  for (int ni = 0; ni < 4; ++ni) {
    int n = wn * 64 + ni * 16 + l15;
    c1[ni] = pb1[n0 + n];
    c2[ni] = pb2[n0 + n];
  }
#pragma unroll
  for (int mi = 0; mi < 4; ++mi) {
#pragma unroll
    for (int reg = 0; reg < 4; ++reg) {
      int m = wm * 64 + mi * 16 + quad * 4 + reg;
      if (m0 + m >= cnt) continue;
#pragma unroll
      for (int ni = 0; ni < 4; ++ni) {
        int n = wn * 64 + ni * 16 + l15;
        float h1 = acc1[mi][ni][reg] + c1[ni];
        float h2 = acc2[mi][ni][reg] + c2[ni];
        float p = h1 * h2;
        float s = p / (1.f + expf(-p));
        outp[(size_t)m * ldo + n] = __float2bfloat16(s);
      }
    }
  }
}

// ---------------- Fused down-projection ----------------
__global__ __launch_bounds__(256, 3) void down_fused(
    const __hip_bfloat16* __restrict__ He, const __hip_bfloat16* __restrict__ Hs,
    const __hip_bfloat16* __restrict__ W3t, const __hip_bfloat16* __restrict__ sw3t,
    const float* __restrict__ b3, const float* __restrict__ sb3,
    const int* __restrict__ counts, const int* __restrict__ offsets,
    const int* __restrict__ ctok, const float* __restrict__ cgate,
    float* __restrict__ out) {
  const int z = blockIdx.z;
  const bool SH = (z == E_CONST);
  const int n0 = blockIdx.x * 128;  // N = 1024 both paths
  const int cnt = SH ? T_CONST : counts[z];
  const int m0 = blockIdx.y * 128;
  if (m0 >= cnt) return;
  const int base = SH ? 0 : offsets[z];
  const int Kd = SH ? SI_CONST : I_CONST;

  const __hip_bfloat16* Ab = SH ? (Hs + (size_t)m0 * SI_CONST)
                                : (He + (size_t)(base + m0) * I_CONST);
  const __hip_bfloat16* Bb = SH ? (sw3t + (size_t)n0 * SI_CONST)
                                : (W3t + ((size_t)z * D_CONST + n0) * I_CONST);

  __shared__ short As[8192], Bs[8192];

  const int tid = threadIdx.x, lane = tid & 63, wv = tid >> 6;
  const int l15 = lane & 15, quad = lane >> 4;
  const int wm = wv & 1, wn = wv >> 1;
  const int lr = lane >> 3, lc = lane & 7, kap = lc ^ lr;

  const __hip_bfloat16 *aG[4], *bG[4];
#pragma unroll
  for (int i = 0; i < 4; ++i) {
    int r = (wv * 4 + i) * 8 + lr;
    aG[i] = Ab + (size_t)r * Kd + kap * 8;
    bG[i] = Bb + (size_t)r * Kd + kap * 8;
  }
  const int ldsu = (wv * 4 * 64 + lane) * 8;

  floatx4 acc[4][4] = {};
  const int kiter = Kd / 64;

  for (int it = 0; it < kiter; ++it) {
#pragma unroll
    for (int i = 0; i < 4; ++i) {
      gload16(aG[i], &As[ldsu + i * 512]);
      gload16(bG[i], &Bs[ldsu + i * 512]);
      aG[i] += 64; bG[i] += 64;
    }
    __syncthreads();
#pragma unroll
    for (int c = 0; c < 2; ++c) {
      const int kc = c * 4 + quad;
      short8 a[4], bbf[4];
#pragma unroll
      for (int mi = 0; mi < 4; ++mi) {
        int m = wm * 64 + mi * 16 + l15;
        a[mi] = *(const short8*)&As[(m * 8 + (kc ^ (m & 7))) * 8];
      }
#pragma unroll
      for (int ni = 0; ni < 4; ++ni) {
        int n = wn * 64 + ni * 16 + l15;
        bbf[ni] = *(const short8*)&Bs[(n * 8 + (kc ^ (n & 7))) * 8];
      }
#pragma unroll
      for (int mi = 0; mi < 4; ++mi)
#pragma unroll
        for (int ni = 0; ni < 4; ++ni)
          acc[mi][ni] = __builtin_amdgcn_mfma_f32_16x16x32_bf16(a[mi], bbf[ni], acc[mi][ni], 0, 0, 0);
    }
    __syncthreads();
  }

  float bias[4];
#pragma unroll
  for (int ni = 0; ni < 4; ++ni) {
    int n = n0 + wn * 64 + ni * 16 + l15;
    bias[ni] = SH ? sb3[n] : b3[(size_t)z * D_CONST + n];
  }
#pragma unroll
  for (int mi = 0; mi < 4; ++mi) {
#pragma unroll
    for (int reg = 0; reg < 4; ++reg) {
      int m = wm * 64 + mi * 16 + quad * 4 + reg;
      if (m0 + m >= cnt) continue;
      int tok;
      float gate;
      if (SH) { tok = m0 + m; gate = 1.f; }
      else { int grow = base + m0 + m; tok = ctok[grow]; gate = cgate[grow]; }
#pragma unroll
      for (int ni = 0; ni < 4; ++ni) {
        int n = n0 + wn * 64 + ni * 16 + l15;
        float v = gate * (acc[mi][ni][reg] + bias[ni]);
        atomicAdd(&out[(size_t)tok * D_CONST + n], v);
      }
    }
  }
}

extern "C" void kernel_launch(void* const* d_in, const int* in_sizes, int n_in,
                              void* d_out, int out_size, void* d_ws, size_t ws_size,
                              hipStream_t stream) {
  const float* x   = (const float*)d_in[0];
  const float* rw  = (const float*)d_in[1];
  const float* rb  = (const float*)d_in[2];
  const float* W1  = (const float*)d_in[3];
  const float* b1  = (const float*)d_in[4];
  const float* W2  = (const float*)d_in[5];
  const float* b2  = (const float*)d_in[6];
  const float* W3  = (const float*)d_in[7];
  const float* b3  = (const float*)d_in[8];
  const float* sw1 = (const float*)d_in[9];
  const float* sb1 = (const float*)d_in[10];
  const float* sw2 = (const float*)d_in[11];
  const float* sb2 = (const float*)d_in[12];
  const float* sw3 = (const float*)d_in[13];
  const float* sb3 = (const float*)d_in[14];
  float* out = (float*)d_out;

  char* w = (char*)d_ws;
  size_t off = 0;
  auto alloc = [&](size_t bytes) {
    char* p = w + off;
    off += (bytes + 255) & ~(size_t)255;
    return p;
  };
  int* counts = (int*)alloc(E_CONST * 4);
  int* offsets = (int*)alloc((E_CONST + 1) * 4);
  int* stok = (int*)alloc((size_t)E_CONST * T_CONST * 4);
  float* gatel = (float*)alloc((size_t)E_CONST * T_CONST * 4);
  float* rwt = (float*)alloc((size_t)D_CONST * E_CONST * 4);
  int* ctok = (int*)alloc((size_t)T_CONST * KSEL * 4);
  float* cgate = (float*)alloc((size_t)T_CONST * KSEL * 4);
  __hip_bfloat16* x_bf = (__hip_bfloat16*)alloc((size_t)T_CONST * D_CONST * 2);
  __hip_bfloat16* Xg = (__hip_bfloat16*)alloc((size_t)(T_CONST * KSEL + 128) * D_CONST * 2);
  __hip_bfloat16* W1t = (__hip_bfloat16*)alloc((size_t)E_CONST * D_CONST * I_CONST * 2);
  __hip_bfloat16* W2t = (__hip_bfloat16*)alloc((size_t)E_CONST * D_CONST * I_CONST * 2);
  __hip_bfloat16* W3t = (__hip_bfloat16*)alloc((size_t)E_CONST * I_CONST * D_CONST * 2);
  __hip_bfloat16* sw1t = (__hip_bfloat16*)alloc((size_t)D_CONST * SI_CONST * 2);
  __hip_bfloat16* sw2t = (__hip_bfloat16*)alloc((size_t)D_CONST * SI_CONST * 2);
  __hip_bfloat16* sw3t = (__hip_bfloat16*)alloc((size_t)SI_CONST * D_CONST * 2);
  __hip_bfloat16* He = (__hip_bfloat16*)alloc((size_t)(T_CONST * KSEL + 128) * I_CONST * 2);
  __hip_bfloat16* Hs = (__hip_bfloat16*)alloc((size_t)T_CONST * SI_CONST * 2);

  hipMemsetAsync(counts, 0, E_CONST * sizeof(int), stream);
  hipMemsetAsync(out, 0, (size_t)out_size * sizeof(float), stream);
  cvt_rwt<<<(D_CONST * E_CONST) / 256, 256, 0, stream>>>(rw, rwt);
  cvt_x<<<(T_CONST * D_CONST) / 1024, 256, 0, stream>>>(x, x_bf);
  transpose_all<<<13056, 256, 0, stream>>>(W1, W2, W3, sw1, sw2, sw3,
                                           W1t, W2t, W3t, sw1t, sw2t, sw3t);
  router2<<<T_CONST / 4, 256, 0, stream>>>(x, rwt, rb, counts, stok, gatel);
  scan_k<<<1, 64, 0, stream>>>(counts, offsets);
  gather_x<<<dim3(E_CONST, T_CONST / 16), 256, 0, stream>>>(
      x_bf, counts, offsets, stok, gatel, Xg, ctok, cgate);
  up_fused<<<dim3(8, 16, E_CONST + 1), 256, 0, stream>>>(
      Xg, x_bf, W1t, W2t, sw1t, sw2t, b1, b2, sb1, sb2, counts, offsets, He, Hs);
  down_fused<<<dim3(8, 16, E_CONST + 1), 256, 0, stream>>>(
      He, Hs, W3t, sw3t, b3, sb3, counts, offsets, ctok, cgate, out);
}